// Round 8
// baseline (1492.558 us; speedup 1.0000x reference)
//
#include <hip/hip_runtime.h>
#include <math.h>

// ---------------------------------------------------------------------------
// PINN beam loss via forward-mode bivariate jets (v8 = v7 + pinned 3 waves/EU).
// Jet of f(z + t*(1,1) + s*(1,0)):  y[k]=coeff t^k, z[k]=coeff t^k s.
// Layer-1: pre-act = p0 + d*t + wx*s  =>  z[k] = (k+1)*(wx/d)*y[k+1] exactly.
//
// Mapping: 64-thread (1-wave) blocks, 4 samples/wave, 16 lanes/sample.
// Layer-2: 8 outputs/lane, stride-16 mapping n2 = g + 16*j with pre-permuted
// weights. amdgpu_waves_per_eu(3,3): VGPR budget 512/3 ~= 170 so the 72-float
// accumulator stays in registers (v7 @ (2,4) spilled it: 387MB scratch writes,
// occupancy capped at 1.8 waves/EU by the scratch allocation).
// LDS per sample (SoA float4 segments, 16B aligned):
//   seg0[k]=(y0,z0,y1,z1)  seg1[k]=(y2,z2,y3,z3)  seg2[k]=(y4,0)
// ---------------------------------------------------------------------------

#define SSTR 648            // per-sample LDS float stride (64*10 + 8 skew)
#define OFF_W2 65536        // ws float offset of W2perm [512][16][8]
#define OFF_W3 131072       // ws float offset of W3perm [128][16][4]

__device__ __forceinline__ float fast_tanh(float x) {
    float ax = fabsf(x);
    float e  = __expf(-2.0f * ax);
    float y  = (1.0f - e) * __builtin_amdgcn_rcpf(1.0f + e);
    return copysignf(y, x);
}

template<int NA, int NB>
__device__ __forceinline__ void tanh_jet(const float (&p)[NA], const float (&q)[NB],
                                         float (&y)[NA], float (&r)[NB]) {
    constexpr int NU = ((NA - 1) > NB ? (NA - 1) : NB);
    float u[NU];
    y[0] = fast_tanh(p[0]);
    u[0] = fmaf(-y[0], y[0], 1.0f);
    if constexpr (NA >= 2) y[1] = u[0] * p[1];
    if constexpr (NU >= 2) u[1] = -2.0f * y[0] * y[1];
    if constexpr (NA >= 3) y[2] = fmaf(u[0], p[2], 0.5f * u[1] * p[1]);
    if constexpr (NU >= 3) u[2] = -fmaf(2.0f * y[0], y[2], y[1] * y[1]);
    if constexpr (NA >= 4) y[3] = fmaf(u[0], p[3], fmaf((2.0f/3.0f) * u[1], p[2],
                                       (1.0f/3.0f) * u[2] * p[1]));
    if constexpr (NU >= 4) u[3] = -2.0f * fmaf(y[0], y[3], y[1] * y[2]);
    if constexpr (NA >= 5) y[4] = fmaf(u[0], p[4], fmaf(0.75f * u[1], p[3],
                                       fmaf(0.5f * u[2], p[2], 0.25f * u[3] * p[1])));
    #pragma unroll
    for (int k = 0; k < NB; ++k) {
        float s = 0.0f;
        #pragma unroll
        for (int j = 0; j <= k; ++j) s = fmaf(u[j], q[k - j], s);
        r[k] = s;
    }
}

// Permute weights for stride-16 per-lane output ownership:
//   W2perm[k*128 + g*8 + j] = W2[k*128 + g + 16*j]   (k<512, g<16, j<8)
//   W3perm[k*64  + g*4 + j] = W3[k*64  + g + 16*j]   (k<128, g<16, j<4)
__global__ __launch_bounds__(256)
void pinn_prep(const float* __restrict__ W2, const float* __restrict__ W3,
               float* __restrict__ ws)
{
    const int i = blockIdx.x * 256 + threadIdx.x;
    if (i < 65536) {
        const int k = i >> 7, r = i & 127, g = r >> 3, j = r & 7;
        ws[OFF_W2 + i] = W2[k * 128 + g + 16 * j];
    }
    if (i < 8192) {
        const int k = i >> 6, r = i & 63, g = r >> 2, j = r & 3;
        ws[OFF_W3 + i] = W3[k * 64 + g + 16 * j];
    }
}

template<int NA, int NB, int TYPE>
__device__ __forceinline__ void eval_body(
    int bi, const float* __restrict__ inp,
    const float* __restrict__ W1, const float* __restrict__ b1,
    const float* __restrict__ W2perm, const float* __restrict__ b2,
    const float* __restrict__ W3perm, const float* __restrict__ b3,
    const float* __restrict__ W4, const float* __restrict__ b4,
    float* __restrict__ ws, int N, int NB0, float* h)
{
    constexpr int JS   = NA + NB;            // 9 / 7 / 3
    constexpr int NS4  = (JS + 1) / 4;       // float4 segments: 2 / 2 / 1
    constexpr int HAS2 = ((JS + 1) & 3) ? 1 : 0;  // trailing float2: 1 / 0 / 0
    constexpr int UNR2 = (NS4 == 2) ? 4 : 8; // layer-2 k-tile
    constexpr int UNR3 = 8;                  // layer-3 k-tile

    const int t  = threadIdx.x;
    const int s  = t >> 4;                   // sample in wave (0..3)
    const int g  = t & 15;                   // lane within sample group
    const int i  = bi * 4 + s;
    const bool valid = (i < N);
    const int ii = valid ? i : (N - 1);

    const float a_in = inp[2 * ii + 1];
    float x_in;
    if constexpr (TYPE == 0)      x_in = inp[2 * ii + 0];
    else if constexpr (TYPE == 1) x_in = 0.0f;
    else                          x_in = 1.0f;

    float* hs  = h + s * SSTR;
    float* s0f = hs;                          // float4[64]
    float* s1f = hs + 256;                    // float4[64] (if NS4==2)
    float* s2f = hs + 512;                    // float2[64] (if HAS2)

    // ---------------- layers 1+2 fused, eight K-chunks of 64 ----------------
    float acc_a[8][NA];
    float acc_b[8][NB];
    #pragma unroll
    for (int j = 0; j < 8; ++j) {
        #pragma unroll
        for (int c = 0; c < NA; ++c) acc_a[j][c] = 0.0f;
        #pragma unroll
        for (int c = 0; c < NB; ++c) acc_b[j][c] = 0.0f;
    }

    for (int ch = 0; ch < 8; ++ch) {
        // ---- layer 1: 64 neurons/sample, 4 per lane ----
        #pragma unroll
        for (int j = 0; j < 4; ++j) {
            const int kl = g + 16 * j;
            const int nn = ch * 64 + kl;
            const float wx = W1[nn];
            const float wa = W1[512 + nn];
            float d = wx + wa;
            if (d == 0.0f) d = 1e-30f;
            const float p0 = fmaf(wx, x_in, fmaf(wa, a_in, b1[nn]));
            const float y0 = fast_tanh(p0);
            const float u0 = fmaf(-y0, y0, 1.0f);
            const float e  = wx * __builtin_amdgcn_rcpf(d);
            float y1 = 0.0f, y2 = 0.0f, y3 = 0.0f, y4 = 0.0f;
            if constexpr (NA >= 2) y1 = u0 * d;
            if constexpr (NA >= 3) { const float u1 = -2.0f * y0 * y1; y2 = 0.5f * u1 * d; }
            if constexpr (NA >= 4) { const float u2 = -fmaf(2.0f * y0, y2, y1 * y1);
                                     y3 = (1.0f/3.0f) * u2 * d; }
            if constexpr (NA >= 5) { const float u3 = -2.0f * fmaf(y0, y3, y1 * y2);
                                     y4 = 0.25f * u3 * d; }
            float4 v0;
            v0.x = y0; v0.y = e * y1; v0.z = y1;
            v0.w = (NB >= 2) ? 2.0f * e * y2 : 0.0f;
            *reinterpret_cast<float4*>(s0f + 4 * kl) = v0;
            if constexpr (NS4 == 2) {
                float4 v1;
                v1.x = y2; v1.y = 3.0f * e * y3;
                v1.z = (NA >= 4) ? y3 : 0.0f;
                v1.w = (NB >= 4) ? 4.0f * e * y4 : 0.0f;
                *reinterpret_cast<float4*>(s1f + 4 * kl) = v1;
            }
            if constexpr (HAS2) {
                float2 v2; v2.x = y4; v2.y = 0.0f;
                *reinterpret_cast<float2*>(s2f + 2 * kl) = v2;
            }
        }
        __syncthreads();

        // ---- layer 2 partial: 64 k's, 8 outputs/lane (n2 = g + 16j) ----
        const float* __restrict__ Wp = W2perm + ch * 8192 + 8 * g;
        #pragma unroll 1
        for (int k0 = 0; k0 < 64; k0 += UNR2) {
            #pragma unroll
            for (int kk = 0; kk < UNR2; ++kk) {
                const int k = k0 + kk;
                const float4 jv0 = *reinterpret_cast<const float4*>(s0f + 4 * k);
                float4 jv1; float2 jv2;
                if constexpr (NS4 == 2) jv1 = *reinterpret_cast<const float4*>(s1f + 4 * k);
                if constexpr (HAS2)     jv2 = *reinterpret_cast<const float2*>(s2f + 2 * k);
                const float4 wva = *reinterpret_cast<const float4*>(Wp + 128 * k);
                const float4 wvb = *reinterpret_cast<const float4*>(Wp + 128 * k + 4);

                float ya[NA], za[NB];
                ya[0] = jv0.x; za[0] = jv0.y; ya[1] = jv0.z;
                if constexpr (NB >= 2) za[1] = jv0.w;
                if constexpr (NS4 == 2) {
                    ya[2] = jv1.x; za[2] = jv1.y;
                    if constexpr (NA >= 4) ya[3] = jv1.z;
                    if constexpr (NB >= 4) za[3] = jv1.w;
                }
                if constexpr (HAS2) ya[4] = jv2.x;
                const float w[8] = {wva.x, wva.y, wva.z, wva.w,
                                    wvb.x, wvb.y, wvb.z, wvb.w};
                #pragma unroll
                for (int j = 0; j < 8; ++j) {
                    #pragma unroll
                    for (int c = 0; c < NA; ++c)
                        acc_a[j][c] = fmaf(w[j], ya[c], acc_a[j][c]);
                    #pragma unroll
                    for (int c = 0; c < NB; ++c)
                        acc_b[j][c] = fmaf(w[j], za[c], acc_b[j][c]);
                }
            }
        }
        __syncthreads();
    }

    // ------- layer-2 activation + layer 3, interleaved two-pass ------------
    // pass p: activate j=4p..4p+3 (their n2 = g+16j lie in [64p, 64p+64)),
    // store those 64 h2 entries, then accumulate layer-3 over k in [64p,..).
    float a3[4][NA], b3c[4][NB];
    #pragma unroll
    for (int j = 0; j < 4; ++j) {
        #pragma unroll
        for (int c = 0; c < NA; ++c) a3[j][c] = 0.0f;
        #pragma unroll
        for (int c = 0; c < NB; ++c) b3c[j][c] = 0.0f;
    }
    #pragma unroll 1
    for (int pass = 0; pass < 2; ++pass) {
        __syncthreads();                     // previous buffer reads done
        #pragma unroll
        for (int jj = 0; jj < 4; ++jj) {
            const int j  = 4 * pass + jj;
            const int n2 = g + 16 * j;
            const int idx = n2 - 64 * pass;  // 0..63
            float pj[NA], qj[NB], yj[NA], rj[NB];
            #pragma unroll
            for (int c = 0; c < NA; ++c) pj[c] = acc_a[j][c];
            pj[0] += b2[n2];
            #pragma unroll
            for (int c = 0; c < NB; ++c) qj[c] = acc_b[j][c];
            tanh_jet<NA, NB>(pj, qj, yj, rj);
            float4 v0;
            v0.x = yj[0]; v0.y = rj[0]; v0.z = (NA >= 2) ? yj[1] : 0.0f;
            v0.w = (NB >= 2) ? rj[1] : 0.0f;
            *reinterpret_cast<float4*>(s0f + 4 * idx) = v0;
            if constexpr (NS4 == 2) {
                float4 v1;
                v1.x = yj[2]; v1.y = rj[2];
                v1.z = (NA >= 4) ? yj[3] : 0.0f;
                v1.w = (NB >= 4) ? rj[3] : 0.0f;
                *reinterpret_cast<float4*>(s1f + 4 * idx) = v1;
            }
            if constexpr (HAS2) {
                float2 v2; v2.x = yj[NA - 1]; v2.y = 0.0f;
                *reinterpret_cast<float2*>(s2f + 2 * idx) = v2;
            }
        }
        __syncthreads();

        const float* __restrict__ W3g = W3perm + pass * 4096 + 4 * g;
        #pragma unroll 1
        for (int k0 = 0; k0 < 64; k0 += UNR3) {
            #pragma unroll
            for (int kk = 0; kk < UNR3; ++kk) {
                const int k = k0 + kk;
                const float4 jv0 = *reinterpret_cast<const float4*>(s0f + 4 * k);
                float4 jv1; float2 jv2;
                if constexpr (NS4 == 2) jv1 = *reinterpret_cast<const float4*>(s1f + 4 * k);
                if constexpr (HAS2)     jv2 = *reinterpret_cast<const float2*>(s2f + 2 * k);
                const float4 wv4 = *reinterpret_cast<const float4*>(W3g + 64 * k);

                float ya[NA], za[NB];
                ya[0] = jv0.x; za[0] = jv0.y; ya[1] = jv0.z;
                if constexpr (NB >= 2) za[1] = jv0.w;
                if constexpr (NS4 == 2) {
                    ya[2] = jv1.x; za[2] = jv1.y;
                    if constexpr (NA >= 4) ya[3] = jv1.z;
                    if constexpr (NB >= 4) za[3] = jv1.w;
                }
                if constexpr (HAS2) ya[4] = jv2.x;
                const float w[4] = {wv4.x, wv4.y, wv4.z, wv4.w};
                #pragma unroll
                for (int j = 0; j < 4; ++j) {
                    #pragma unroll
                    for (int c = 0; c < NA; ++c)
                        a3[j][c] = fmaf(w[j], ya[c], a3[j][c]);
                    #pragma unroll
                    for (int c = 0; c < NB; ++c)
                        b3c[j][c] = fmaf(w[j], za[c], b3c[j][c]);
                }
            }
        }
    }

    // ---------------- layer 4 + loss (4 n3/lane, n3 = g + 16j) -------------
    float part[JS];
    #pragma unroll
    for (int c = 0; c < JS; ++c) part[c] = 0.0f;
    #pragma unroll
    for (int j = 0; j < 4; ++j) {
        const int n3 = g + 16 * j;
        float pj[NA], qj[NB], yj[NA], rj[NB];
        #pragma unroll
        for (int c = 0; c < NA; ++c) pj[c] = a3[j][c];
        pj[0] += b3[n3];
        #pragma unroll
        for (int c = 0; c < NB; ++c) qj[c] = b3c[j][c];
        tanh_jet<NA, NB>(pj, qj, yj, rj);
        const float w4 = W4[n3];
        #pragma unroll
        for (int c = 0; c < NA; ++c) part[c] = fmaf(w4, yj[c], part[c]);
        #pragma unroll
        for (int c = 0; c < NB; ++c) part[NA + c] = fmaf(w4, rj[c], part[NA + c]);
    }
    #pragma unroll
    for (int m = 1; m <= 8; m <<= 1)
        #pragma unroll
        for (int c = 0; c < JS; ++c)
            part[c] += __shfl_xor(part[c], m, 64);
    // all 16 lanes of each group now hold their sample's output jet

    const float A0 = part[0] + b4[0];
    float t0 = 0.0f, t1 = 0.0f, t2 = 0.0f;
    constexpr float CC = 1.0f;   // P/(E*I)
    if constexpr (TYPE == 0) {
        const float gx = 6.0f * part[NA + 3];
        const float ga = 24.0f * part[4] - gx;
        t0 = (gx + CC) * (gx + CC) + (ga + CC) * (ga + CC);
    }
    if constexpr (TYPE == 1) {
        t0 = A0 * A0;
        const float gx = part[NA + 0];
        const float ga = part[1] - gx;
        t1 = gx * gx + ga * ga;
    }
    if constexpr (TYPE == 2) {
        const float wa = a_in * A0;
        t0 = wa * wa;
        const float g2x = part[NA + 1];
        const float g2a = 2.0f * part[2] - g2x;
        t1 = g2x * g2x + g2a * g2a;
        const float g3x = 2.0f * part[NA + 2];
        const float g3a = 6.0f * part[3] - g3x;
        const float om = 1.0f - a_in;
        t2 = om * om * (g3x * g3x + g3a * g3a);
    }
    if (!valid) { t0 = 0.0f; t1 = 0.0f; t2 = 0.0f; }

    // sum the wave's 4 samples (cross-group butterflies)
    t0 += __shfl_xor(t0, 16, 64); t0 += __shfl_xor(t0, 32, 64);
    if constexpr (TYPE != 0) { t1 += __shfl_xor(t1, 16, 64); t1 += __shfl_xor(t1, 32, 64); }
    if constexpr (TYPE == 2) { t2 += __shfl_xor(t2, 16, 64); t2 += __shfl_xor(t2, 32, 64); }

    if (t == 0) {
        if constexpr (TYPE == 0) {
            ws[bi] = t0;
        } else if constexpr (TYPE == 1) {
            ws[NB0 + bi]     = t0;
            ws[2 * NB0 + bi] = t1;
        } else {
            ws[3 * NB0 + bi] = t0;
            ws[4 * NB0 + bi] = t1;
            ws[5 * NB0 + bi] = t2;
        }
    }
}

__global__ __launch_bounds__(64)
__attribute__((amdgpu_waves_per_eu(3, 3)))
void pinn_fat(const float* __restrict__ inp,
              const float* __restrict__ W1, const float* __restrict__ b1,
              const float* __restrict__ W2perm, const float* __restrict__ b2,
              const float* __restrict__ W3perm, const float* __restrict__ b3,
              const float* __restrict__ W4, const float* __restrict__ b4,
              float* __restrict__ ws, int N, int NB0)
{
    __shared__ __align__(16) float h[4 * SSTR];    // 10368 B
    const int b = blockIdx.x;
    if (b < NB0)
        eval_body<5, 4, 0>(b, inp, W1, b1, W2perm, b2, W3perm, b3, W4, b4, ws, N, NB0, h);
    else if (b < 2 * NB0)
        eval_body<4, 3, 2>(b - NB0, inp, W1, b1, W2perm, b2, W3perm, b3, W4, b4, ws, N, NB0, h);
    else
        eval_body<2, 1, 1>(b - 2 * NB0, inp, W1, b1, W2perm, b2, W3perm, b3, W4, b4, ws, N, NB0, h);
}

__global__ __launch_bounds__(1024)
void pinn_reduce(const float* __restrict__ ws, float* __restrict__ out,
                 int G, float invN, float inv2N)
{
    __shared__ float sh[16 * 6];
    float s[6];
    #pragma unroll
    for (int q = 0; q < 6; ++q) {
        float acc = 0.0f;
        for (int i = threadIdx.x; i < G; i += 1024) acc += ws[q * G + i];
        #pragma unroll
        for (int m = 1; m <= 32; m <<= 1) acc += __shfl_xor(acc, m, 64);
        s[q] = acc;
    }
    const int wid = threadIdx.x >> 6;
    if ((threadIdx.x & 63) == 0) {
        #pragma unroll
        for (int q = 0; q < 6; ++q) sh[wid * 6 + q] = s[q];
    }
    __syncthreads();
    if (threadIdx.x == 0) {
        float r[6];
        #pragma unroll
        for (int q = 0; q < 6; ++q) {
            float acc = 0.0f;
            for (int w = 0; w < 16; ++w) acc += sh[w * 6 + q];
            r[q] = acc;
        }
        const float pde   = r[0] * inv2N;
        const float w0    = r[1] * invN;
        const float w0x   = r[2] * inv2N;
        const float wL    = r[3] * invN;
        const float wLxx  = r[4] * inv2N;
        const float wLxxx = r[5] * inv2N;
        out[0] = pde + w0 + w0x + wL + wLxx + wLxxx;
        out[1] = pde;
        out[2] = w0;
        out[3] = w0x;
        out[4] = wL;
        out[5] = wLxx;
        out[6] = wLxxx;
    }
}

extern "C" void kernel_launch(void* const* d_in, const int* in_sizes, int n_in,
                              void* d_out, int out_size, void* d_ws, size_t ws_size,
                              hipStream_t stream) {
    const float* inp = (const float*)d_in[0];
    const float* W1  = (const float*)d_in[1];
    const float* b1  = (const float*)d_in[2];
    const float* W2  = (const float*)d_in[3];
    const float* b2  = (const float*)d_in[4];
    const float* W3  = (const float*)d_in[5];
    const float* b3  = (const float*)d_in[6];
    const float* W4  = (const float*)d_in[7];
    const float* b4  = (const float*)d_in[8];
    float* ws  = (float*)d_ws;
    float* out = (float*)d_out;

    const int N   = in_sizes[0] / 2;   // 32768
    const int NB0 = (N + 3) / 4;       // blocks per eval type (4 samples/block)

    // permute W2/W3 for stride-16 lane->output ownership (into d_ws)
    pinn_prep<<<dim3(256), dim3(256), 0, stream>>>(W2, W3, ws);

    pinn_fat<<<dim3(3 * NB0), dim3(64), 0, stream>>>(
        inp, W1, b1, ws + OFF_W2, b2, ws + OFF_W3, b3, W4, b4, ws, N, NB0);
    pinn_reduce<<<dim3(1), dim3(1024), 0, stream>>>(
        ws, out, NB0, 1.0f / (float)N, 0.5f / (float)N);
}

// Round 9
// 1192.681 us; speedup vs baseline: 1.2514x; 1.2514x over previous
//
#include <hip/hip_runtime.h>
#include <math.h>

// ---------------------------------------------------------------------------
// PINN beam loss via forward-mode bivariate jets (v9: scratch-free).
// Jet of f(z + t*(1,1) + s*(1,0)):  y[k]=coeff t^k, z[k]=coeff t^k s.
// Layer-1: pre-act = p0 + d*t + wx*s  =>  z[k] = (k+1)*(wx/d)*y[k+1] exactly.
//
// Mapping: 64-thread (1-wave) blocks, 4 samples/wave, 16 lanes/sample.
// Layer-2: 8 outputs/lane, stride-16 mapping n2 = g + 16*j, pre-permuted W.
// v8 bug (rule #20): acc_a[4*pass+jj] with runtime `pass` demoted the whole
// 72-float accumulator to scratch (1.7 GB HBM writes). Fix: fully unroll the
// pass loop. Also halve the k-tile (UNR2=2) so in-flight loads (36 floats)
// + acc (72) fit ~130 VGPRs spill-free under __launch_bounds__(64,2).
// LDS per sample (SoA float4 segments, 16B aligned):
//   seg0[k]=(y0,z0,y1,z1)  seg1[k]=(y2,z2,y3,z3)  seg2[k]=(y4,0)
// ---------------------------------------------------------------------------

#define SSTR 648            // per-sample LDS float stride (64*10 + 8 skew)
#define OFF_W2 65536        // ws float offset of W2perm [512][16][8]
#define OFF_W3 131072       // ws float offset of W3perm [128][16][4]

__device__ __forceinline__ float fast_tanh(float x) {
    float ax = fabsf(x);
    float e  = __expf(-2.0f * ax);
    float y  = (1.0f - e) * __builtin_amdgcn_rcpf(1.0f + e);
    return copysignf(y, x);
}

template<int NA, int NB>
__device__ __forceinline__ void tanh_jet(const float (&p)[NA], const float (&q)[NB],
                                         float (&y)[NA], float (&r)[NB]) {
    constexpr int NU = ((NA - 1) > NB ? (NA - 1) : NB);
    float u[NU];
    y[0] = fast_tanh(p[0]);
    u[0] = fmaf(-y[0], y[0], 1.0f);
    if constexpr (NA >= 2) y[1] = u[0] * p[1];
    if constexpr (NU >= 2) u[1] = -2.0f * y[0] * y[1];
    if constexpr (NA >= 3) y[2] = fmaf(u[0], p[2], 0.5f * u[1] * p[1]);
    if constexpr (NU >= 3) u[2] = -fmaf(2.0f * y[0], y[2], y[1] * y[1]);
    if constexpr (NA >= 4) y[3] = fmaf(u[0], p[3], fmaf((2.0f/3.0f) * u[1], p[2],
                                       (1.0f/3.0f) * u[2] * p[1]));
    if constexpr (NU >= 4) u[3] = -2.0f * fmaf(y[0], y[3], y[1] * y[2]);
    if constexpr (NA >= 5) y[4] = fmaf(u[0], p[4], fmaf(0.75f * u[1], p[3],
                                       fmaf(0.5f * u[2], p[2], 0.25f * u[3] * p[1])));
    #pragma unroll
    for (int k = 0; k < NB; ++k) {
        float s = 0.0f;
        #pragma unroll
        for (int j = 0; j <= k; ++j) s = fmaf(u[j], q[k - j], s);
        r[k] = s;
    }
}

// Permute weights for stride-16 per-lane output ownership:
//   W2perm[k*128 + g*8 + j] = W2[k*128 + g + 16*j]   (k<512, g<16, j<8)
//   W3perm[k*64  + g*4 + j] = W3[k*64  + g + 16*j]   (k<128, g<16, j<4)
__global__ __launch_bounds__(256)
void pinn_prep(const float* __restrict__ W2, const float* __restrict__ W3,
               float* __restrict__ ws)
{
    const int i = blockIdx.x * 256 + threadIdx.x;
    if (i < 65536) {
        const int k = i >> 7, r = i & 127, g = r >> 3, j = r & 7;
        ws[OFF_W2 + i] = W2[k * 128 + g + 16 * j];
    }
    if (i < 8192) {
        const int k = i >> 6, r = i & 63, g = r >> 2, j = r & 3;
        ws[OFF_W3 + i] = W3[k * 64 + g + 16 * j];
    }
}

template<int NA, int NB, int TYPE>
__device__ __forceinline__ void eval_body(
    int bi, const float* __restrict__ inp,
    const float* __restrict__ W1, const float* __restrict__ b1,
    const float* __restrict__ W2perm, const float* __restrict__ b2,
    const float* __restrict__ W3perm, const float* __restrict__ b3,
    const float* __restrict__ W4, const float* __restrict__ b4,
    float* __restrict__ ws, int N, int NB0, float* h)
{
    constexpr int JS   = NA + NB;            // 9 / 7 / 3
    constexpr int NS4  = (JS + 1) / 4;       // float4 segments: 2 / 2 / 1
    constexpr int HAS2 = ((JS + 1) & 3) ? 1 : 0;  // trailing float2: 1 / 0 / 0
    constexpr int UNR2 = (NS4 == 2) ? 2 : 8; // layer-2 k-tile (keep live set small)
    constexpr int UNR3 = (NS4 == 2) ? 4 : 8; // layer-3 k-tile

    const int t  = threadIdx.x;
    const int s  = t >> 4;                   // sample in wave (0..3)
    const int g  = t & 15;                   // lane within sample group
    const int i  = bi * 4 + s;
    const bool valid = (i < N);
    const int ii = valid ? i : (N - 1);

    const float a_in = inp[2 * ii + 1];
    float x_in;
    if constexpr (TYPE == 0)      x_in = inp[2 * ii + 0];
    else if constexpr (TYPE == 1) x_in = 0.0f;
    else                          x_in = 1.0f;

    float* hs  = h + s * SSTR;
    float* s0f = hs;                          // float4[64]
    float* s1f = hs + 256;                    // float4[64] (if NS4==2)
    float* s2f = hs + 512;                    // float2[64] (if HAS2)

    // ---------------- layers 1+2 fused, eight K-chunks of 64 ----------------
    float acc_a[8][NA];
    float acc_b[8][NB];
    #pragma unroll
    for (int j = 0; j < 8; ++j) {
        #pragma unroll
        for (int c = 0; c < NA; ++c) acc_a[j][c] = 0.0f;
        #pragma unroll
        for (int c = 0; c < NB; ++c) acc_b[j][c] = 0.0f;
    }

    for (int ch = 0; ch < 8; ++ch) {
        // ---- layer 1: 64 neurons/sample, 4 per lane ----
        #pragma unroll
        for (int j = 0; j < 4; ++j) {
            const int kl = g + 16 * j;
            const int nn = ch * 64 + kl;
            const float wx = W1[nn];
            const float wa = W1[512 + nn];
            float d = wx + wa;
            if (d == 0.0f) d = 1e-30f;
            const float p0 = fmaf(wx, x_in, fmaf(wa, a_in, b1[nn]));
            const float y0 = fast_tanh(p0);
            const float u0 = fmaf(-y0, y0, 1.0f);
            const float e  = wx * __builtin_amdgcn_rcpf(d);
            float y1 = 0.0f, y2 = 0.0f, y3 = 0.0f, y4 = 0.0f;
            if constexpr (NA >= 2) y1 = u0 * d;
            if constexpr (NA >= 3) { const float u1 = -2.0f * y0 * y1; y2 = 0.5f * u1 * d; }
            if constexpr (NA >= 4) { const float u2 = -fmaf(2.0f * y0, y2, y1 * y1);
                                     y3 = (1.0f/3.0f) * u2 * d; }
            if constexpr (NA >= 5) { const float u3 = -2.0f * fmaf(y0, y3, y1 * y2);
                                     y4 = 0.25f * u3 * d; }
            float4 v0;
            v0.x = y0; v0.y = e * y1; v0.z = y1;
            v0.w = (NB >= 2) ? 2.0f * e * y2 : 0.0f;
            *reinterpret_cast<float4*>(s0f + 4 * kl) = v0;
            if constexpr (NS4 == 2) {
                float4 v1;
                v1.x = y2; v1.y = 3.0f * e * y3;
                v1.z = (NA >= 4) ? y3 : 0.0f;
                v1.w = (NB >= 4) ? 4.0f * e * y4 : 0.0f;
                *reinterpret_cast<float4*>(s1f + 4 * kl) = v1;
            }
            if constexpr (HAS2) {
                float2 v2; v2.x = y4; v2.y = 0.0f;
                *reinterpret_cast<float2*>(s2f + 2 * kl) = v2;
            }
        }
        __syncthreads();

        // ---- layer 2 partial: 64 k's, 8 outputs/lane (n2 = g + 16j) ----
        const float* __restrict__ Wp = W2perm + ch * 8192 + 8 * g;
        #pragma unroll 1
        for (int k0 = 0; k0 < 64; k0 += UNR2) {
            #pragma unroll
            for (int kk = 0; kk < UNR2; ++kk) {
                const int k = k0 + kk;
                const float4 jv0 = *reinterpret_cast<const float4*>(s0f + 4 * k);
                float4 jv1; float2 jv2;
                if constexpr (NS4 == 2) jv1 = *reinterpret_cast<const float4*>(s1f + 4 * k);
                if constexpr (HAS2)     jv2 = *reinterpret_cast<const float2*>(s2f + 2 * k);
                const float4 wva = *reinterpret_cast<const float4*>(Wp + 128 * k);
                const float4 wvb = *reinterpret_cast<const float4*>(Wp + 128 * k + 4);

                float ya[NA], za[NB];
                ya[0] = jv0.x; za[0] = jv0.y; ya[1] = jv0.z;
                if constexpr (NB >= 2) za[1] = jv0.w;
                if constexpr (NS4 == 2) {
                    ya[2] = jv1.x; za[2] = jv1.y;
                    if constexpr (NA >= 4) ya[3] = jv1.z;
                    if constexpr (NB >= 4) za[3] = jv1.w;
                }
                if constexpr (HAS2) ya[4] = jv2.x;
                const float w[8] = {wva.x, wva.y, wva.z, wva.w,
                                    wvb.x, wvb.y, wvb.z, wvb.w};
                #pragma unroll
                for (int j = 0; j < 8; ++j) {
                    #pragma unroll
                    for (int c = 0; c < NA; ++c)
                        acc_a[j][c] = fmaf(w[j], ya[c], acc_a[j][c]);
                    #pragma unroll
                    for (int c = 0; c < NB; ++c)
                        acc_b[j][c] = fmaf(w[j], za[c], acc_b[j][c]);
                }
            }
        }
        __syncthreads();
    }

    // ------- layer-2 activation + layer 3, interleaved two-pass ------------
    // pass p (FULLY UNROLLED -> all acc indexing compile-time, rule #20):
    // activate j=4p..4p+3 (n2 = g+16j in [64p,64p+64)), store those 64 h2
    // entries, then accumulate layer-3 over that half's k range.
    float a3[4][NA], b3c[4][NB];
    #pragma unroll
    for (int j = 0; j < 4; ++j) {
        #pragma unroll
        for (int c = 0; c < NA; ++c) a3[j][c] = 0.0f;
        #pragma unroll
        for (int c = 0; c < NB; ++c) b3c[j][c] = 0.0f;
    }
    #pragma unroll
    for (int pass = 0; pass < 2; ++pass) {
        __syncthreads();                     // previous buffer reads done
        #pragma unroll
        for (int jj = 0; jj < 4; ++jj) {
            const int j  = 4 * pass + jj;
            const int n2 = g + 16 * j;
            const int idx = n2 - 64 * pass;  // 0..63
            float pj[NA], qj[NB], yj[NA], rj[NB];
            #pragma unroll
            for (int c = 0; c < NA; ++c) pj[c] = acc_a[j][c];
            pj[0] += b2[n2];
            #pragma unroll
            for (int c = 0; c < NB; ++c) qj[c] = acc_b[j][c];
            tanh_jet<NA, NB>(pj, qj, yj, rj);
            float4 v0;
            v0.x = yj[0]; v0.y = rj[0]; v0.z = (NA >= 2) ? yj[1] : 0.0f;
            v0.w = (NB >= 2) ? rj[1] : 0.0f;
            *reinterpret_cast<float4*>(s0f + 4 * idx) = v0;
            if constexpr (NS4 == 2) {
                float4 v1;
                v1.x = yj[2]; v1.y = rj[2];
                v1.z = (NA >= 4) ? yj[3] : 0.0f;
                v1.w = (NB >= 4) ? rj[3] : 0.0f;
                *reinterpret_cast<float4*>(s1f + 4 * idx) = v1;
            }
            if constexpr (HAS2) {
                float2 v2; v2.x = yj[NA - 1]; v2.y = 0.0f;
                *reinterpret_cast<float2*>(s2f + 2 * idx) = v2;
            }
        }
        __syncthreads();

        const float* __restrict__ W3g = W3perm + pass * 4096 + 4 * g;
        #pragma unroll 1
        for (int k0 = 0; k0 < 64; k0 += UNR3) {
            #pragma unroll
            for (int kk = 0; kk < UNR3; ++kk) {
                const int k = k0 + kk;
                const float4 jv0 = *reinterpret_cast<const float4*>(s0f + 4 * k);
                float4 jv1; float2 jv2;
                if constexpr (NS4 == 2) jv1 = *reinterpret_cast<const float4*>(s1f + 4 * k);
                if constexpr (HAS2)     jv2 = *reinterpret_cast<const float2*>(s2f + 2 * k);
                const float4 wv4 = *reinterpret_cast<const float4*>(W3g + 64 * k);

                float ya[NA], za[NB];
                ya[0] = jv0.x; za[0] = jv0.y; ya[1] = jv0.z;
                if constexpr (NB >= 2) za[1] = jv0.w;
                if constexpr (NS4 == 2) {
                    ya[2] = jv1.x; za[2] = jv1.y;
                    if constexpr (NA >= 4) ya[3] = jv1.z;
                    if constexpr (NB >= 4) za[3] = jv1.w;
                }
                if constexpr (HAS2) ya[4] = jv2.x;
                const float w[4] = {wv4.x, wv4.y, wv4.z, wv4.w};
                #pragma unroll
                for (int j = 0; j < 4; ++j) {
                    #pragma unroll
                    for (int c = 0; c < NA; ++c)
                        a3[j][c] = fmaf(w[j], ya[c], a3[j][c]);
                    #pragma unroll
                    for (int c = 0; c < NB; ++c)
                        b3c[j][c] = fmaf(w[j], za[c], b3c[j][c]);
                }
            }
        }
    }

    // ---------------- layer 4 + loss (4 n3/lane, n3 = g + 16j) -------------
    float part[JS];
    #pragma unroll
    for (int c = 0; c < JS; ++c) part[c] = 0.0f;
    #pragma unroll
    for (int j = 0; j < 4; ++j) {
        const int n3 = g + 16 * j;
        float pj[NA], qj[NB], yj[NA], rj[NB];
        #pragma unroll
        for (int c = 0; c < NA; ++c) pj[c] = a3[j][c];
        pj[0] += b3[n3];
        #pragma unroll
        for (int c = 0; c < NB; ++c) qj[c] = b3c[j][c];
        tanh_jet<NA, NB>(pj, qj, yj, rj);
        const float w4 = W4[n3];
        #pragma unroll
        for (int c = 0; c < NA; ++c) part[c] = fmaf(w4, yj[c], part[c]);
        #pragma unroll
        for (int c = 0; c < NB; ++c) part[NA + c] = fmaf(w4, rj[c], part[NA + c]);
    }
    #pragma unroll
    for (int m = 1; m <= 8; m <<= 1)
        #pragma unroll
        for (int c = 0; c < JS; ++c)
            part[c] += __shfl_xor(part[c], m, 64);
    // all 16 lanes of each group now hold their sample's output jet

    const float A0 = part[0] + b4[0];
    float t0 = 0.0f, t1 = 0.0f, t2 = 0.0f;
    constexpr float CC = 1.0f;   // P/(E*I)
    if constexpr (TYPE == 0) {
        const float gx = 6.0f * part[NA + 3];
        const float ga = 24.0f * part[4] - gx;
        t0 = (gx + CC) * (gx + CC) + (ga + CC) * (ga + CC);
    }
    if constexpr (TYPE == 1) {
        t0 = A0 * A0;
        const float gx = part[NA + 0];
        const float ga = part[1] - gx;
        t1 = gx * gx + ga * ga;
    }
    if constexpr (TYPE == 2) {
        const float wa = a_in * A0;
        t0 = wa * wa;
        const float g2x = part[NA + 1];
        const float g2a = 2.0f * part[2] - g2x;
        t1 = g2x * g2x + g2a * g2a;
        const float g3x = 2.0f * part[NA + 2];
        const float g3a = 6.0f * part[3] - g3x;
        const float om = 1.0f - a_in;
        t2 = om * om * (g3x * g3x + g3a * g3a);
    }
    if (!valid) { t0 = 0.0f; t1 = 0.0f; t2 = 0.0f; }

    // sum the wave's 4 samples (cross-group butterflies)
    t0 += __shfl_xor(t0, 16, 64); t0 += __shfl_xor(t0, 32, 64);
    if constexpr (TYPE != 0) { t1 += __shfl_xor(t1, 16, 64); t1 += __shfl_xor(t1, 32, 64); }
    if constexpr (TYPE == 2) { t2 += __shfl_xor(t2, 16, 64); t2 += __shfl_xor(t2, 32, 64); }

    if (t == 0) {
        if constexpr (TYPE == 0) {
            ws[bi] = t0;
        } else if constexpr (TYPE == 1) {
            ws[NB0 + bi]     = t0;
            ws[2 * NB0 + bi] = t1;
        } else {
            ws[3 * NB0 + bi] = t0;
            ws[4 * NB0 + bi] = t1;
            ws[5 * NB0 + bi] = t2;
        }
    }
}

__global__ __launch_bounds__(64, 2)
void pinn_fat(const float* __restrict__ inp,
              const float* __restrict__ W1, const float* __restrict__ b1,
              const float* __restrict__ W2perm, const float* __restrict__ b2,
              const float* __restrict__ W3perm, const float* __restrict__ b3,
              const float* __restrict__ W4, const float* __restrict__ b4,
              float* __restrict__ ws, int N, int NB0)
{
    __shared__ __align__(16) float h[4 * SSTR];    // 10368 B
    const int b = blockIdx.x;
    if (b < NB0)
        eval_body<5, 4, 0>(b, inp, W1, b1, W2perm, b2, W3perm, b3, W4, b4, ws, N, NB0, h);
    else if (b < 2 * NB0)
        eval_body<4, 3, 2>(b - NB0, inp, W1, b1, W2perm, b2, W3perm, b3, W4, b4, ws, N, NB0, h);
    else
        eval_body<2, 1, 1>(b - 2 * NB0, inp, W1, b1, W2perm, b2, W3perm, b3, W4, b4, ws, N, NB0, h);
}

__global__ __launch_bounds__(1024)
void pinn_reduce(const float* __restrict__ ws, float* __restrict__ out,
                 int G, float invN, float inv2N)
{
    __shared__ float sh[16 * 6];
    float s[6];
    #pragma unroll
    for (int q = 0; q < 6; ++q) {
        float acc = 0.0f;
        for (int i = threadIdx.x; i < G; i += 1024) acc += ws[q * G + i];
        #pragma unroll
        for (int m = 1; m <= 32; m <<= 1) acc += __shfl_xor(acc, m, 64);
        s[q] = acc;
    }
    const int wid = threadIdx.x >> 6;
    if ((threadIdx.x & 63) == 0) {
        #pragma unroll
        for (int q = 0; q < 6; ++q) sh[wid * 6 + q] = s[q];
    }
    __syncthreads();
    if (threadIdx.x == 0) {
        float r[6];
        #pragma unroll
        for (int q = 0; q < 6; ++q) {
            float acc = 0.0f;
            for (int w = 0; w < 16; ++w) acc += sh[w * 6 + q];
            r[q] = acc;
        }
        const float pde   = r[0] * inv2N;
        const float w0    = r[1] * invN;
        const float w0x   = r[2] * inv2N;
        const float wL    = r[3] * invN;
        const float wLxx  = r[4] * inv2N;
        const float wLxxx = r[5] * inv2N;
        out[0] = pde + w0 + w0x + wL + wLxx + wLxxx;
        out[1] = pde;
        out[2] = w0;
        out[3] = w0x;
        out[4] = wL;
        out[5] = wLxx;
        out[6] = wLxxx;
    }
}

extern "C" void kernel_launch(void* const* d_in, const int* in_sizes, int n_in,
                              void* d_out, int out_size, void* d_ws, size_t ws_size,
                              hipStream_t stream) {
    const float* inp = (const float*)d_in[0];
    const float* W1  = (const float*)d_in[1];
    const float* b1  = (const float*)d_in[2];
    const float* W2  = (const float*)d_in[3];
    const float* b2  = (const float*)d_in[4];
    const float* W3  = (const float*)d_in[5];
    const float* b3  = (const float*)d_in[6];
    const float* W4  = (const float*)d_in[7];
    const float* b4  = (const float*)d_in[8];
    float* ws  = (float*)d_ws;
    float* out = (float*)d_out;

    const int N   = in_sizes[0] / 2;   // 32768
    const int NB0 = (N + 3) / 4;       // blocks per eval type (4 samples/block)

    // permute W2/W3 for stride-16 lane->output ownership (into d_ws)
    pinn_prep<<<dim3(256), dim3(256), 0, stream>>>(W2, W3, ws);

    pinn_fat<<<dim3(3 * NB0), dim3(64), 0, stream>>>(
        inp, W1, b1, ws + OFF_W2, b2, ws + OFF_W3, b3, W4, b4, ws, N, NB0);
    pinn_reduce<<<dim3(1), dim3(1024), 0, stream>>>(
        ws, out, NB0, 1.0f / (float)N, 0.5f / (float)N);
}